// Round 4
// baseline (114.935 us; speedup 1.0000x reference)
//
#include <hip/hip_runtime.h>

// TemporalPyramidPooling R4: work-split waves for occupancy.
// (w,stride) = (4,2), (8,4), (16,8) over x[8,4096,512] fp32.
// Per (b,tile of 32 starts): 4 waves. Waves 0,1 (d-halves) produce the w=4
// outputs (rows t0..t0+33); waves 2,3 produce w=8 and w=16 (rows t0..t0+39).
// Same x lines read twice -> second read hits L1/L2/L3 (x=64MB < 256MB L3),
// HBM fetch unchanged, but resident waves double: 4096 waves = 16/CU,
// in-flight ~9.5 KB/CU >= Little's-law requirement for 6.3 TB/s.
// Barrier-free, LDS-free; mask math wave-uniform in registers.

#define EPS 1e-6f

typedef float f4 __attribute__((ext_vector_type(4)));

constexpr int B = 8, T = 4096, D = 512, D4 = D / 4;
constexpr int TILE = 32;          // window starts per tile
constexpr int NTILES = T / TILE;  // 128
constexpr int S4 = 2047, S8 = 1023, S16 = 511;

constexpr size_t OFF0 = 0;                           // avg4  [B,S4,D]
constexpr size_t OFF1 = (size_t)B * S4 * D;          // avg8  [B,S8,D]
constexpr size_t OFF2 = OFF1 + (size_t)B * S8 * D;   // avg16 [B,S16,D]
constexpr size_t OFF3 = OFF2 + (size_t)B * S16 * D;  // mask4 [B,S4]
constexpr size_t OFF4 = OFF3 + (size_t)B * S4;       // mask8 [B,S8]
constexpr size_t OFF5 = OFF4 + (size_t)B * S8;       // mask16[B,S16]

__device__ __forceinline__ float rcp_clip(float c) {
  return __builtin_amdgcn_rcpf(fmaxf(c, EPS));  // |err|~1ulp << 0.08 thresh
}

// ---- w=4 scale: windows j=0..15, rows t0..t0+33, pairs 0..16 ----
template <bool GUARD>
__device__ __forceinline__ void w4_body(const f4* __restrict__ xb,
                                        const int* __restrict__ mp,
                                        float* __restrict__ out, int b,
                                        int tile, int d4, int lane,
                                        bool wmask) {
  const int t0 = tile * TILE;
  float mf[34];
#pragma unroll
  for (int i = 0; i < 34; ++i) {
    int m = (!GUARD || (t0 + i) < T) ? mp[i] : 0;
    mf[i] = (m != 0) ? 1.0f : 0.0f;
  }
  float c4[16];
#pragma unroll
  for (int j = 0; j < 16; ++j)
    c4[j] = (mf[2 * j] + mf[2 * j + 1]) + (mf[2 * j + 2] + mf[2 * j + 3]);

  if (wmask && lane < 16) {
    int s = tile * 16 + lane;
    if (!GUARD || s < S4) {
      float c = 0.f;
#pragma unroll
      for (int j = 0; j < 16; ++j) c = (lane == j) ? c4[j] : c;
      out[OFF3 + (size_t)b * S4 + s] = (c > 0.f) ? 1.f : 0.f;
    }
  }

  f4 p[17];
#pragma unroll
  for (int i = 0; i < 17; ++i) {
    int t = t0 + 2 * i;
    f4 a0 = {0.f, 0.f, 0.f, 0.f}, a1 = {0.f, 0.f, 0.f, 0.f};
    if (!GUARD || t < T) {  // t even: t<T implies t+1<T
      a0 = xb[(size_t)t * D4];
      a1 = xb[(size_t)(t + 1) * D4];
    }
    p[i] = a0 * mf[2 * i] + a1 * mf[2 * i + 1];
  }

  f4* o4 = (f4*)(out + OFF0) + ((size_t)b * S4 + (size_t)tile * 16) * D4 + d4;
#pragma unroll
  for (int j = 0; j < 16; ++j) {
    if (!GUARD || (tile * 16 + j) < S4) {
      f4 v = (p[j] + p[j + 1]) * rcp_clip(c4[j]);
      __builtin_nontemporal_store(v, o4 + (size_t)j * D4);
    }
  }
}

// ---- w=8 + w=16 scales: rows t0..t0+39, pairs 0..19 ----
template <bool GUARD>
__device__ __forceinline__ void w816_body(const f4* __restrict__ xb,
                                          const int* __restrict__ mp,
                                          float* __restrict__ out, int b,
                                          int tile, int d4, int lane,
                                          bool wmask) {
  const int t0 = tile * TILE;
  float mf[40];
#pragma unroll
  for (int i = 0; i < 40; ++i) {
    int m = (!GUARD || (t0 + i) < T) ? mp[i] : 0;
    mf[i] = (m != 0) ? 1.0f : 0.0f;
  }
  float c8[9];
#pragma unroll
  for (int k = 0; k < 9; ++k) {
    float c = 0.f;
#pragma unroll
    for (int i = 0; i < 8; ++i) c += mf[4 * k + i];
    c8[k] = c;
  }
  float c16[4];
#pragma unroll
  for (int l = 0; l < 4; ++l) c16[l] = c8[2 * l] + c8[2 * l + 2];

  if (wmask) {
    if (lane < 8) {
      int s = tile * 8 + lane;
      if (!GUARD || s < S8) {
        float c = 0.f;
#pragma unroll
        for (int j = 0; j < 8; ++j) c = (lane == j) ? c8[j] : c;
        out[OFF4 + (size_t)b * S8 + s] = (c > 0.f) ? 1.f : 0.f;
      }
    } else if (lane < 12) {
      int l = lane - 8, s = tile * 4 + l;
      if (!GUARD || s < S16) {
        float c = 0.f;
#pragma unroll
        for (int j = 0; j < 4; ++j) c = (l == j) ? c16[j] : c;
        out[OFF5 + (size_t)b * S16 + s] = (c > 0.f) ? 1.f : 0.f;
      }
    }
  }

  f4 p[20];
#pragma unroll
  for (int i = 0; i < 20; ++i) {
    int t = t0 + 2 * i;
    f4 a0 = {0.f, 0.f, 0.f, 0.f}, a1 = {0.f, 0.f, 0.f, 0.f};
    if (!GUARD || t < T) {
      a0 = xb[(size_t)t * D4];
      a1 = xb[(size_t)(t + 1) * D4];
    }
    p[i] = a0 * mf[2 * i] + a1 * mf[2 * i + 1];
  }

  f4 q8[9];
#pragma unroll
  for (int k = 0; k < 9; ++k)
    q8[k] = (p[2 * k] + p[2 * k + 1]) + (p[2 * k + 2] + p[2 * k + 3]);

  f4* o8 = (f4*)(out + OFF1) + ((size_t)b * S8 + (size_t)tile * 8) * D4 + d4;
#pragma unroll
  for (int k = 0; k < 8; ++k) {
    if (!GUARD || (tile * 8 + k) < S8) {
      f4 v = q8[k] * rcp_clip(c8[k]);
      __builtin_nontemporal_store(v, o8 + (size_t)k * D4);
    }
  }

  f4* o16 = (f4*)(out + OFF2) + ((size_t)b * S16 + (size_t)tile * 4) * D4 + d4;
#pragma unroll
  for (int l = 0; l < 4; ++l) {
    if (!GUARD || (tile * 4 + l) < S16) {
      f4 v = (q8[2 * l] + q8[2 * l + 2]) * rcp_clip(c16[l]);
      __builtin_nontemporal_store(v, o16 + (size_t)l * D4);
    }
  }
}

__global__ __launch_bounds__(256, 4)  // 4 waves/EU -> 4 blocks/CU = 16 waves
void tpp_kernel(const f4* __restrict__ x4, const int* __restrict__ mask,
                float* __restrict__ out) {
  const int tid = threadIdx.x;
  const int wid = tid >> 6;       // 0..3
  const int lane = tid & 63;
  const int dhalf = wid & 1;
  const int d4 = dhalf * 64 + lane;
  const int b = blockIdx.z;
  const int tile = blockIdx.y;

  const f4* xb = x4 + (size_t)b * T * D4 + d4;
  const int* mp = mask + (size_t)b * T + tile * TILE;
  const bool last = (tile == NTILES - 1);

  if (wid < 2) {
    if (!last)
      w4_body<false>(xb, mp, out, b, tile, d4, lane, wid == 0);
    else
      w4_body<true>(xb, mp, out, b, tile, d4, lane, wid == 0);
  } else {
    if (!last)
      w816_body<false>(xb, mp, out, b, tile, d4, lane, wid == 2);
    else
      w816_body<true>(xb, mp, out, b, tile, d4, lane, wid == 2);
  }
}

extern "C" void kernel_launch(void* const* d_in, const int* in_sizes, int n_in,
                              void* d_out, int out_size, void* d_ws,
                              size_t ws_size, hipStream_t stream) {
  const f4* x4 = (const f4*)d_in[0];
  const int* mask = (const int*)d_in[1];
  float* out = (float*)d_out;
  dim3 grid(1, NTILES, B);  // 1024 blocks x 4 waves = 4096 waves
  tpp_kernel<<<grid, 256, 0, stream>>>(x4, mask, out);
}

// Round 5
// 110.192 us; speedup vs baseline: 1.0430x; 1.0430x over previous
//
#include <hip/hip_runtime.h>

// TemporalPyramidPooling R5: streaming pyramid, O(1) carried state.
// (w,stride) = (4,2), (8,4), (16,8) over x[8,4096,512] fp32.
// Per wave: one (b, tile-of-64-starts, d-half) column. Iterate over groups
// of 8 rows (= 4 masked pairs); each iteration emits 4 w4-, 2 w8-, 1 w16-
// output rows using current pairs + carries {P3 = last pair, H = last 2
// pairs, G = group sum}. Loads prefetched 2 groups ahead into 3 rotating
// register buffers (the %3 reuse creates WAR deps that stop the compiler
// from hoisting everything -> ~180 VGPRs, not 300+). Loads and stores
// interleave every iteration (no read-phase/write-phase separation).
// TILE=64 -> halo 8/64 = 12.5% overfetch. Last tile = 8 iterations, no
// guards needed anywhere.

#define EPS 1e-6f

typedef float f4 __attribute__((ext_vector_type(4)));

constexpr int B = 8, T = 4096, D = 512, D4 = D / 4;
constexpr int TILE = 64;          // window starts per tile
constexpr int NTILES = T / TILE;  // 64
constexpr int S4 = 2047, S8 = 1023, S16 = 511;

constexpr size_t OFF0 = 0;                           // avg4  [B,S4,D]
constexpr size_t OFF1 = (size_t)B * S4 * D;          // avg8  [B,S8,D]
constexpr size_t OFF2 = OFF1 + (size_t)B * S8 * D;   // avg16 [B,S16,D]
constexpr size_t OFF3 = OFF2 + (size_t)B * S16 * D;  // mask4 [B,S4]
constexpr size_t OFF4 = OFF3 + (size_t)B * S4;       // mask8 [B,S8]
constexpr size_t OFF5 = OFF4 + (size_t)B * S8;       // mask16[B,S16]

__device__ __forceinline__ float rcp_clip(float c) {
  return __builtin_amdgcn_rcpf(fmaxf(c, EPS));  // ~1ulp err << 0.08 thresh
}

// NU = 9 for tiles 0..62 (groups 0..8, rows t0..t0+71);
// NU = 8 for tile 63 (groups 0..7, rows t0..t0+63 = T-1; outputs j=31,
// k=15, l=7 are globally out of range and simply never emitted).
template <int NU>
__device__ __forceinline__ void run_tile(const f4* __restrict__ xb,
                                         const int* __restrict__ mp,
                                         float* __restrict__ out, int b,
                                         int tile, int d4, int lane,
                                         bool wmask) {
  f4 buf[3][8];
  float mfb[3][8];

  // preload groups 0 and 1
#pragma unroll
  for (int g = 0; g < 2 && g < NU; ++g) {
#pragma unroll
    for (int rr = 0; rr < 8; ++rr) {
      buf[g][rr] = xb[(size_t)(8 * g + rr) * D4];
      mfb[g][rr] = (mp[8 * g + rr] != 0) ? 1.f : 0.f;
    }
  }

  f4 P3 = {0.f, 0.f, 0.f, 0.f}, H = {0.f, 0.f, 0.f, 0.f},
     G = {0.f, 0.f, 0.f, 0.f};
  float cP3 = 0.f, cH = 0.f, cG = 0.f;

  f4* o4 = (f4*)(out + OFF0) + ((size_t)b * S4 + (size_t)tile * 32) * D4 + d4;
  f4* o8 = (f4*)(out + OFF1) + ((size_t)b * S8 + (size_t)tile * 16) * D4 + d4;
  f4* o16 = (f4*)(out + OFF2) + ((size_t)b * S16 + (size_t)tile * 8) * D4 + d4;
  float* m4 = out + OFF3 + (size_t)b * S4 + (size_t)tile * 32;
  float* m8 = out + OFF4 + (size_t)b * S8 + (size_t)tile * 16;
  float* m16 = out + OFF5 + (size_t)b * S16 + (size_t)tile * 8;

#pragma unroll
  for (int u = 0; u < NU; ++u) {
    // prefetch group u+2 into the rotating buffer
    if (u + 2 < NU) {
#pragma unroll
      for (int rr = 0; rr < 8; ++rr) {
        buf[(u + 2) % 3][rr] = xb[(size_t)(8 * (u + 2) + rr) * D4];
        mfb[(u + 2) % 3][rr] = (mp[8 * (u + 2) + rr] != 0) ? 1.f : 0.f;
      }
    }

    const f4* r = buf[u % 3];
    const float* mf = mfb[u % 3];

    // 4 masked pairs of this group
    f4 pr0 = r[0] * mf[0] + r[1] * mf[1];
    f4 pr1 = r[2] * mf[2] + r[3] * mf[3];
    f4 pr2 = r[4] * mf[4] + r[5] * mf[5];
    f4 pr3 = r[6] * mf[6] + r[7] * mf[7];
    float c0 = mf[0] + mf[1], c1 = mf[2] + mf[3];
    float c2 = mf[4] + mf[5], c3 = mf[6] + mf[7];
    f4 Gc = (pr0 + pr1) + (pr2 + pr3);
    float cGc = (c0 + c1) + (c2 + c3);

    // carry-based outputs (windows straddling the group boundary)
    if (u >= 1) {
      f4 v;
      v = (P3 + pr0) * rcp_clip(cP3 + c0);  // w4 j = 4u-1: pairs {4u-1,4u}
      __builtin_nontemporal_store(v, o4 + (size_t)(4 * u - 1) * D4);
      v = (H + (pr0 + pr1)) * rcp_clip(cH + c0 + c1);  // w8 k = 2u-1
      __builtin_nontemporal_store(v, o8 + (size_t)(2 * u - 1) * D4);
      v = (G + Gc) * rcp_clip(cG + cGc);  // w16 l = u-1: groups {u-1,u}
      __builtin_nontemporal_store(v, o16 + (size_t)(u - 1) * D4);
    }
    // in-group outputs (local j <= 30, k <= 14 -> only when u < 8)
    if (u < 8) {
      f4 v;
      v = (pr0 + pr1) * rcp_clip(c0 + c1);  // w4 j = 4u
      __builtin_nontemporal_store(v, o4 + (size_t)(4 * u + 0) * D4);
      v = (pr1 + pr2) * rcp_clip(c1 + c2);  // w4 j = 4u+1
      __builtin_nontemporal_store(v, o4 + (size_t)(4 * u + 1) * D4);
      v = (pr2 + pr3) * rcp_clip(c2 + c3);  // w4 j = 4u+2
      __builtin_nontemporal_store(v, o4 + (size_t)(4 * u + 2) * D4);
      v = Gc * rcp_clip(cGc);  // w8 k = 2u
      __builtin_nontemporal_store(v, o8 + (size_t)(2 * u) * D4);
    }

    // mask outputs: 7 wave-uniform scalars, one lane each (wmask wave only)
    if (wmask) {
      float cc = 0.f;
      float* ap = nullptr;
      if (u < 8) {
        if (lane == 0) { cc = c0 + c1; ap = m4 + 4 * u; }
        else if (lane == 1) { cc = c1 + c2; ap = m4 + 4 * u + 1; }
        else if (lane == 2) { cc = c2 + c3; ap = m4 + 4 * u + 2; }
        else if (lane == 4) { cc = cGc; ap = m8 + 2 * u; }
      }
      if (u >= 1) {
        if (lane == 3) { cc = cP3 + c0; ap = m4 + 4 * u - 1; }
        else if (lane == 5) { cc = cH + c0 + c1; ap = m8 + 2 * u - 1; }
        else if (lane == 6) { cc = cG + cGc; ap = m16 + u - 1; }
      }
      if (ap) *ap = (cc > 0.f) ? 1.f : 0.f;
    }

    // update carries
    P3 = pr3; H = pr2 + pr3; G = Gc;
    cP3 = c3; cH = c2 + c3; cG = cGc;
  }
}

__global__ __launch_bounds__(64)
void tpp_kernel(const f4* __restrict__ x4, const int* __restrict__ mask,
                float* __restrict__ out) {
  const int lane = threadIdx.x;            // 0..63
  const int d4 = blockIdx.x * 64 + lane;   // 0..127
  const int b = blockIdx.z;
  const int tile = blockIdx.y;
  const bool wmask = (blockIdx.x == 0);

  const f4* xb = x4 + ((size_t)b * T + (size_t)tile * TILE) * D4 + d4;
  const int* mp = mask + (size_t)b * T + tile * TILE;

  if (tile < NTILES - 1)
    run_tile<9>(xb, mp, out, b, tile, d4, lane, wmask);
  else
    run_tile<8>(xb, mp, out, b, tile, d4, lane, wmask);
}

extern "C" void kernel_launch(void* const* d_in, const int* in_sizes, int n_in,
                              void* d_out, int out_size, void* d_ws,
                              size_t ws_size, hipStream_t stream) {
  const f4* x4 = (const f4*)d_in[0];
  const int* mask = (const int*)d_in[1];
  float* out = (float*)d_out;
  dim3 grid(D4 / 64, NTILES, B);  // (2,64,8) = 1024 single-wave blocks
  tpp_kernel<<<grid, 64, 0, stream>>>(x4, mask, out);
}